// Round 8
// baseline (667.355 us; speedup 1.0000x reference)
//
#include <hip/hip_runtime.h>

// LSTM: SEQ=4096, BATCH=4096, IN=2, HID=8, fp32.
// R14 = R13 + trans-issue grind (trans is the binding pipe: ~16cy/instr
// per wave, no cross-wave co-issue -- established via R11 vs R12/R13).
//  - PAIRED RCP: r0=1/(1+e0), r1=1/(1+e1) via ONE v_rcp:
//      q = rcp(d0*d1); r0 = q*d1; r1 = q*d0.
//    5 trans/step (e0,e1,q,e2,r2) = the floor for this layout; was 6.
//  - RAW-r0 gf exchange: hf1's raw r0 IS sigma_f, so gf = ror8(r0)
//    directly -- act0-fma leaves the gf->c-fma serial path (act0 now only
//    feeds pp on hf0; tm0 uniform = -2L2E).
//  - everything else = R13 verified: 16 lanes/batch (l16 = hf*8+u; hf0
//    owns rows (i,g~), hf1 owns (f,o)), packed split-dots (7-DPP tree +
//    8 pk_fma + 2 hadds), all-lane c/h, 3 bank-masked ror8 exchanges,
//    x-init + prefetch + ngo gap-filled into the exp2/rcp shadows,
//    grid 256 x block 256 = 1024 waves = 1 wave/SIMD on all 256 CUs.
// Numerics: rows pre-scaled by -log2e (-2log2e for g~), c kept in scaled
// space c' = -2*log2e*c, sigmoid/tanh via exp2+rcp only. Paired-rcp adds
// ~2^-21 relative error to the gate sigmoids (negligible vs 2^-10 absmax).

#define SEQ   4096
#define BATCH 4096
#define PF    8

#define DPP_X1   0xB1  // quad_perm [1,0,3,2] : lane ^ 1
#define DPP_X2   0x4E  // quad_perm [2,3,0,1] : lane ^ 2
#define DPP_X3   0x1B  // quad_perm [3,2,1,0] : lane ^ 3
#define DPP_HMIR 0x141 // row_half_mirror     : lane ^ 7 (within 8-lane half)
#define DPP_ROR8 0x128 // row_ror:8           : lane ^ 8 (within 16-lane row)

typedef float v2f __attribute__((ext_vector_type(2)));

template<int CTRL>
__device__ __forceinline__ float rot(float v) {
    int i = __builtin_bit_cast(int, v);
    int r = __builtin_amdgcn_update_dpp(0, i, CTRL, 0xf, 0xf, true);
    return __builtin_bit_cast(float, r);
}
template<int CTRL>
__device__ __forceinline__ v2f dpp2(v2f v) {
    v2f r; r.x = rot<CTRL>(v.x); r.y = rot<CTRL>(v.y); return r;
}
// ror8 with bank-masked merge: lanes in enabled BANKS receive src[l^8],
// disabled banks keep 'oldv'. banks 0,1 = lanes 0-7 of each 16-lane row.
template<int BANKS>
__device__ __forceinline__ float ror8_keep(float oldv, float src) {
    int o = __builtin_bit_cast(int, oldv);
    int s = __builtin_bit_cast(int, src);
    int r = __builtin_amdgcn_update_dpp(o, s, DPP_ROR8, 0xf, BANKS, false);
    return __builtin_bit_cast(float, r);
}
__device__ __forceinline__ v2f vfma(v2f a, v2f b, v2f c) {
    return __builtin_elementwise_fma(a, b, c);
}

__global__ __launch_bounds__(256, 1) void lstm_kernel(
    const float* __restrict__ x,    // (SEQ, BATCH, 2)
    const float* __restrict__ h0,   // (1, BATCH, 8)
    const float* __restrict__ c0,   // (1, BATCH, 8)
    const float* __restrict__ Wih,  // (32, 2)
    const float* __restrict__ Whh,  // (32, 8)
    const float* __restrict__ bih,  // (32)
    const float* __restrict__ bhh,  // (32)
    float* __restrict__ out)        // (1, BATCH, 8)
{
    const int tid = threadIdx.x;
    const int l16 = tid & 15;
    const int u   = l16 & 7;         // unit 0..7
    const int hf  = l16 >> 3;        // 0: rows (i,g~)   1: rows (f,o)
    const int b   = blockIdx.x * 16 + (tid >> 4);

    const int row0 = hf * 8 + u;      // i-row (0..7)  or f-row (8..15)
    const int row1 = 16 + row0;       // g~-row (16..23) or o-row (24..31)

    const float L2E = 1.4426950408889634f;
    const float n2L = -2.0f * L2E;
    // pre-activation scales folded into weights:
    //   sigmoid rows (i,f,o): -L2E     tanh row (g~): -2*L2E
    const float smul0 = -L2E;
    const float smul1 = hf ? -L2E : n2L;
    // act0 = r0 * n2L = gi on hf0 (-2L2E*sigma_i); unused on hf1 (gf is
    // exchanged RAW). act1 = fma(r1,2,addc1): gg (tanh) on hf0, go2 on hf1.
    const float addc1 = hf ? 0.0f : -1.0f;

    // weights paired for split-dot: pair m covers columns (u^m, u^m^7)
    const float* wr0 = Whh + row0 * 8;
    const float* wr1 = Whh + row1 * 8;
    v2f W0[4], W1[4];
#pragma unroll
    for (int m = 0; m < 4; ++m) {
        const int ka = u ^ m, kb = ka ^ 7;
        W0[m] = (v2f){ wr0[ka], wr0[kb] } * smul0;
        W1[m] = (v2f){ wr1[ka], wr1[kb] } * smul1;
    }
    const v2f WX0 = (v2f){ Wih[2 * row0], Wih[2 * row0 + 1] } * smul0;
    const v2f WX1 = (v2f){ Wih[2 * row1], Wih[2 * row1 + 1] } * smul1;
    const v2f B0  = { (bih[row0] + bhh[row0]) * smul0, 0.0f };
    const v2f B1  = { (bih[row1] + bhh[row1]) * smul1, 0.0f };

    // state: c in scaled space c' = -2*L2E*c; valid in ALL lanes
    float c = c0[b * 8 + u] * n2L;
    float h = h0[b * 8 + u];

    const float2* __restrict__ xp2 = (const float2*)x;
    float2 xb[PF];
#pragma unroll
    for (int p = 0; p < PF; ++p) xb[p] = xp2[p * BATCH + b];

    // carried next-step init accumulators (h-independent x-part of the dot)
    v2f a0n, a1n;
    {
        const v2f xv0 = { xb[0].x, xb[0].y };
        a0n = vfma(xv0, WX0, B0);
        a1n = vfma(xv0, WX1, B1);
    }

    for (int s = 0; s < SEQ; s += PF) {
#pragma unroll
        for (int p = 0; p < PF; ++p) {
            v2f a0 = a0n, a1 = a1n;   // init was precomputed in a trans gap

            // ---- h-gather: P_m = (h_{u^m}, h_{u^m^7}); 7 DPPs total
            v2f P0; P0.x = h; P0.y = rot<DPP_HMIR>(h);
            const v2f P1 = dpp2<DPP_X1>(P0);
            const v2f P2 = dpp2<DPP_X2>(P0);
            const v2f P3 = dpp2<DPP_X3>(P0);

            // ---- two packed split-dots (one per owned row)
            a0 = vfma(P0, W0[0], a0);  a1 = vfma(P0, W1[0], a1);
            a0 = vfma(P1, W0[1], a0);  a1 = vfma(P1, W1[1], a1);
            a0 = vfma(P2, W0[2], a0);  a1 = vfma(P2, W1[2], a1);
            a0 = vfma(P3, W0[3], a0);  a1 = vfma(P3, W1[3], a1);
            const float pre0 = a0.x + a0.y;            // already scaled
            const float pre1 = a1.x + a1.y;

            // ---- gate activations: 2 exp2 + ONE paired rcp
            const float e0 = __builtin_amdgcn_exp2f(pre0);
            const float e1 = __builtin_amdgcn_exp2f(pre1);

            // [gap-fill: x prefetch for slot p, independent of everything]
            const int sn = (s + p + PF) & (SEQ - 1);   // uniform wrap
            xb[p] = xp2[sn * BATCH + b];

            const float d0 = e0 + 1.0f;
            const float d1 = e1 + 1.0f;
            const float q  = __builtin_amdgcn_rcpf(d0 * d1);
            const float r0 = q * d1;                   // 1/(1+e0)
            const float r1 = q * d0;                   // 1/(1+e1)

            // ---- exchanges: gf from RAW r0 (hf1's r0 IS sigma_f)
            const float gf   = ror8_keep<0x3>(r0, r0);    // all: sigma_f
            const float act0 = r0 * n2L;                  // hf0: gi
            const float act1 = __builtin_fmaf(r1, 2.0f, addc1); // gg | go2
            const float go2  = ror8_keep<0x3>(act1, act1);// all: 2*sigma_o
            const float pp   = act0 * act1;               // hf0: gi*gg
            const float ig   = ror8_keep<0xC>(pp, pp);    // all: gi*gg

            // ---- c/h update in ALL lanes (h replicated by construction)
            c = __builtin_fmaf(gf, c, ig);             // scaled-c recurrence
            const float e2 = __builtin_amdgcn_exp2f(c);

            // [gap-fill inside the c-exp2 shadow: next-step x-init + ngo]
            const float2 xcn = xb[(p + 1) & (PF - 1)];
            const v2f xvn = { xcn.x, xcn.y };
            a0n = vfma(xvn, WX0, B0);
            a1n = vfma(xvn, WX1, B1);
            const float ngo = go2 * -0.5f;

            const float r2 = __builtin_amdgcn_rcpf(e2 + 1.0f);
            h = __builtin_fmaf(go2, r2, ngo);          // h = 2sig*r - sig
        }
    }

    if (!hf) out[b * 8 + u] = h;
}

extern "C" void kernel_launch(void* const* d_in, const int* in_sizes, int n_in,
                              void* d_out, int out_size, void* d_ws, size_t ws_size,
                              hipStream_t stream) {
    const float* x   = (const float*)d_in[0];
    const float* h0  = (const float*)d_in[1];
    const float* c0  = (const float*)d_in[2];
    const float* Wih = (const float*)d_in[3];
    const float* Whh = (const float*)d_in[4];
    const float* bih = (const float*)d_in[5];
    const float* bhh = (const float*)d_in[6];
    float* out = (float*)d_out;

    dim3 grid(BATCH / 16);   // 256 blocks -> 1 block/CU on all 256 CUs
    dim3 block(256);         // 4 waves/block -> 1 wave/SIMD (full chip)
    hipLaunchKernelGGL(lstm_kernel, grid, block, 0, stream,
                       x, h0, c0, Wih, Whh, bih, bhh, out);
}

// Round 9
// 657.579 us; speedup vs baseline: 1.0149x; 1.0149x over previous
//
#include <hip/hip_runtime.h>

// LSTM: SEQ=4096, BATCH=4096, IN=2, HID=8, fp32.
// R15 = R13 (best: 533us) + path-only trims. R14 post-mortem: paired-rcp
// didn't cut issue (trans issue ~8cy not 16) and lengthened the gate path
// (mul->rcp->mul); reverted. Kept/added only strictly path/issue-positive:
//  - raw-r0 gf exchange (hf1's raw r0 IS sigma_f): one mul off the
//    gf->c-fma path vs R13.
//  - packed activation finalize: (act0,act1) = pk_fma((r0,r1),
//    {-2L2E,2},{0,addc}) -- one v_pk_fma_f32 replaces mul+fma.
//  - everything else R13 verbatim: 16 lanes/batch (l16=hf*8+u; hf0 owns
//    rows (i,g~), hf1 owns (f,o)), packed split-dots (7-DPP tree + 8
//    pk_fma + 2 hadds), all-lane c/h, 3 bank-masked ror8 exchanges,
//    x-init + x-prefetch + ngo gap-filled into the trans shadows,
//    grid 256 x block 256 = 1024 waves = 1 wave/SIMD on all 256 CUs.
// Numerics: rows pre-scaled by -log2e (-2log2e for g~), c in scaled space
// c' = -2*log2e*c, sigmoid/tanh via exp2+rcp only.

#define SEQ   4096
#define BATCH 4096
#define PF    8

#define DPP_X1   0xB1  // quad_perm [1,0,3,2] : lane ^ 1
#define DPP_X2   0x4E  // quad_perm [2,3,0,1] : lane ^ 2
#define DPP_X3   0x1B  // quad_perm [3,2,1,0] : lane ^ 3
#define DPP_HMIR 0x141 // row_half_mirror     : lane ^ 7 (within 8-lane half)
#define DPP_ROR8 0x128 // row_ror:8           : lane ^ 8 (within 16-lane row)

typedef float v2f __attribute__((ext_vector_type(2)));

template<int CTRL>
__device__ __forceinline__ float rot(float v) {
    int i = __builtin_bit_cast(int, v);
    int r = __builtin_amdgcn_update_dpp(0, i, CTRL, 0xf, 0xf, true);
    return __builtin_bit_cast(float, r);
}
template<int CTRL>
__device__ __forceinline__ v2f dpp2(v2f v) {
    v2f r; r.x = rot<CTRL>(v.x); r.y = rot<CTRL>(v.y); return r;
}
// ror8 with bank-masked merge: lanes in enabled BANKS receive src[l^8],
// disabled banks keep 'oldv'. banks 0,1 = lanes 0-7 of each 16-lane row.
template<int BANKS>
__device__ __forceinline__ float ror8_keep(float oldv, float src) {
    int o = __builtin_bit_cast(int, oldv);
    int s = __builtin_bit_cast(int, src);
    int r = __builtin_amdgcn_update_dpp(o, s, DPP_ROR8, 0xf, BANKS, false);
    return __builtin_bit_cast(float, r);
}
__device__ __forceinline__ v2f vfma(v2f a, v2f b, v2f c) {
    return __builtin_elementwise_fma(a, b, c);
}

__global__ __launch_bounds__(256, 1) void lstm_kernel(
    const float* __restrict__ x,    // (SEQ, BATCH, 2)
    const float* __restrict__ h0,   // (1, BATCH, 8)
    const float* __restrict__ c0,   // (1, BATCH, 8)
    const float* __restrict__ Wih,  // (32, 2)
    const float* __restrict__ Whh,  // (32, 8)
    const float* __restrict__ bih,  // (32)
    const float* __restrict__ bhh,  // (32)
    float* __restrict__ out)        // (1, BATCH, 8)
{
    const int tid = threadIdx.x;
    const int l16 = tid & 15;
    const int u   = l16 & 7;         // unit 0..7
    const int hf  = l16 >> 3;        // 0: rows (i,g~)   1: rows (f,o)
    const int b   = blockIdx.x * 16 + (tid >> 4);

    const int row0 = hf * 8 + u;      // i-row (0..7)  or f-row (8..15)
    const int row1 = 16 + row0;       // g~-row (16..23) or o-row (24..31)

    const float L2E = 1.4426950408889634f;
    const float n2L = -2.0f * L2E;
    // pre-activation scales folded into weights:
    //   sigmoid rows (i,f,o): -L2E     tanh row (g~): -2*L2E
    const float smul0 = -L2E;
    const float smul1 = hf ? -L2E : n2L;
    // packed finalize: (act0,act1) = pk_fma((r0,r1), {n2L,2}, {0,addc1})
    //   hf0: act0 = gi (-2L2E*sigma_i), act1 = gg (tanh)
    //   hf1: act0 unused (gf exchanged RAW), act1 = go2 (2*sigma_o)
    const v2f actm = { n2L, 2.0f };
    const v2f acta = { 0.0f, hf ? 0.0f : -1.0f };

    // weights paired for split-dot: pair m covers columns (u^m, u^m^7)
    const float* wr0 = Whh + row0 * 8;
    const float* wr1 = Whh + row1 * 8;
    v2f W0[4], W1[4];
#pragma unroll
    for (int m = 0; m < 4; ++m) {
        const int ka = u ^ m, kb = ka ^ 7;
        W0[m] = (v2f){ wr0[ka], wr0[kb] } * smul0;
        W1[m] = (v2f){ wr1[ka], wr1[kb] } * smul1;
    }
    const v2f WX0 = (v2f){ Wih[2 * row0], Wih[2 * row0 + 1] } * smul0;
    const v2f WX1 = (v2f){ Wih[2 * row1], Wih[2 * row1 + 1] } * smul1;
    const v2f B0  = { (bih[row0] + bhh[row0]) * smul0, 0.0f };
    const v2f B1  = { (bih[row1] + bhh[row1]) * smul1, 0.0f };

    // state: c in scaled space c' = -2*L2E*c; valid in ALL lanes
    float c = c0[b * 8 + u] * n2L;
    float h = h0[b * 8 + u];

    const float2* __restrict__ xp2 = (const float2*)x;
    float2 xb[PF];
#pragma unroll
    for (int p = 0; p < PF; ++p) xb[p] = xp2[p * BATCH + b];

    // carried next-step init accumulators (h-independent x-part of the dot)
    v2f a0n, a1n;
    {
        const v2f xv0 = { xb[0].x, xb[0].y };
        a0n = vfma(xv0, WX0, B0);
        a1n = vfma(xv0, WX1, B1);
    }

    for (int s = 0; s < SEQ; s += PF) {
#pragma unroll
        for (int p = 0; p < PF; ++p) {
            v2f a0 = a0n, a1 = a1n;   // init was precomputed in a trans gap

            // ---- h-gather: P_m = (h_{u^m}, h_{u^m^7}); 7 DPPs total
            v2f P0; P0.x = h; P0.y = rot<DPP_HMIR>(h);
            const v2f P1 = dpp2<DPP_X1>(P0);
            const v2f P2 = dpp2<DPP_X2>(P0);
            const v2f P3 = dpp2<DPP_X3>(P0);

            // ---- two packed split-dots (one per owned row)
            a0 = vfma(P0, W0[0], a0);  a1 = vfma(P0, W1[0], a1);
            a0 = vfma(P1, W0[1], a0);  a1 = vfma(P1, W1[1], a1);
            a0 = vfma(P2, W0[2], a0);  a1 = vfma(P2, W1[2], a1);
            a0 = vfma(P3, W0[3], a0);  a1 = vfma(P3, W1[3], a1);
            const float pre0 = a0.x + a0.y;            // already scaled
            const float pre1 = a1.x + a1.y;

            // ---- gate activations (two direct rcps: shortest path, R13)
            const float e0 = __builtin_amdgcn_exp2f(pre0);
            const float e1 = __builtin_amdgcn_exp2f(pre1);

            // [gap-fill: x prefetch for slot p, independent of everything]
            const int sn = (s + p + PF) & (SEQ - 1);   // uniform wrap
            xb[p] = xp2[sn * BATCH + b];

            const float r0 = __builtin_amdgcn_rcpf(e0 + 1.0f);
            const float r1 = __builtin_amdgcn_rcpf(e1 + 1.0f);

            // ---- gf from RAW r0 (hf1's r0 IS sigma_f); packed finalize
            const float gf  = ror8_keep<0x3>(r0, r0);     // all: sigma_f
            v2f rr; rr.x = r0; rr.y = r1;
            const v2f act = vfma(rr, actm, acta);         // (gi|-, gg|go2)
            const float go2 = ror8_keep<0x3>(act.y, act.y); // all: 2*sig_o
            const float pp  = act.x * act.y;              // hf0: gi*gg
            const float ig  = ror8_keep<0xC>(pp, pp);     // all: gi*gg

            // ---- c/h update in ALL lanes (h replicated by construction)
            c = __builtin_fmaf(gf, c, ig);             // scaled-c recurrence
            const float e2 = __builtin_amdgcn_exp2f(c);

            // [gap-fill inside the c-exp2 shadow: next-step x-init + ngo]
            const float2 xcn = xb[(p + 1) & (PF - 1)];
            const v2f xvn = { xcn.x, xcn.y };
            a0n = vfma(xvn, WX0, B0);
            a1n = vfma(xvn, WX1, B1);
            const float ngo = go2 * -0.5f;

            const float r2 = __builtin_amdgcn_rcpf(e2 + 1.0f);
            h = __builtin_fmaf(go2, r2, ngo);          // h = 2sig*r - sig
        }
    }

    if (!hf) out[b * 8 + u] = h;
}

extern "C" void kernel_launch(void* const* d_in, const int* in_sizes, int n_in,
                              void* d_out, int out_size, void* d_ws, size_t ws_size,
                              hipStream_t stream) {
    const float* x   = (const float*)d_in[0];
    const float* h0  = (const float*)d_in[1];
    const float* c0  = (const float*)d_in[2];
    const float* Wih = (const float*)d_in[3];
    const float* Whh = (const float*)d_in[4];
    const float* bih = (const float*)d_in[5];
    const float* bhh = (const float*)d_in[6];
    float* out = (float*)d_out;

    dim3 grid(BATCH / 16);   // 256 blocks -> 1 block/CU on all 256 CUs
    dim3 block(256);         // 4 waves/block -> 1 wave/SIMD (full chip)
    hipLaunchKernelGGL(lstm_kernel, grid, block, 0, stream,
                       x, h0, c0, Wih, Whh, bih, bhh, out);
}